// Round 12
// baseline (897.143 us; speedup 1.0000x reference)
//
#include <hip/hip_runtime.h>
#include <hip/hip_fp16.h>
#include <hip/hip_bf16.h>
#include <math.h>

typedef __attribute__((ext_vector_type(8))) short short8b;    // 8 bf16 = 4 VGPR
typedef __attribute__((ext_vector_type(4))) float f32x4;      // 16x16 MFMA acc
typedef __attribute__((ext_vector_type(16))) float f32x16;    // 32x32 MFMA acc
typedef __attribute__((ext_vector_type(4))) unsigned short ushort4b;

#define NWIN 8192
#define NT   512
#define SCALE 0.18257418583505536f   // 30^-0.5

// ---- LDS geometry (element pitches) ----
#define XB_P 200    // xb [64][200] bf16; x cols 0..179 + pad 180..191 zero
#define QK_P 200    // qk [64][200] bf16 per pass: head hh: q @ hh*64, k @ hh*64+32 (pads auto-zero)
#define VT_P 72     // vT per head [32][72] bf16; rows 30,31 auto-zero; cols = permuted tok
#define DB_P 68     // dB [64][68] f16
#define ATT_P 184   // att in global (d_out upper half): [64][184] bf16, cols h*30+dd

// ---- LDS offsets (bytes) ----
#define OFF_XB   0                // 25600
#define OFF_QK   25600            // 25600
#define OFF_VT   51200            // 13824 (3 heads x 32*72*2)
#define OFF_DB   65024            // 8704
#define OFF_BPE  73728            // 5120  (bpe [64][20] f32)
#define OFF_QKVB 78848            // 2304  (qkvb [576] f32, seg*32+dd, dd>=30 -> 0)
#define LDS_BYTES 81152           // x2 = 162304 <= 163840 -> 2 blocks/CU

#define WK 192

__device__ __forceinline__ unsigned int bf2pk(float lo, float hi) {
    union { __hip_bfloat162 h; unsigned int u; } cv;
    cv.h = __float22bfloat162_rn(make_float2(lo, hi));
    return cv.u;
}
__device__ __forceinline__ unsigned short bf1(float v) {
    union { __hip_bfloat16 h; unsigned short u; } cv;
    cv.h = __float2bfloat16(v);
    return cv.u;
}

// wqr: [540][192] bf16. Row r = seg*30+dd, seg = which*6+hh_global, dd 0..29.
// wpr: [192][192] bf16 plain (pad rows/cols zero).
// d_ws total: 207360 + 73728 = 281088 B (proven-safe envelope).
__global__ void prep_weights(const float* __restrict__ qkv_w,
                             const float* __restrict__ proj_w,
                             unsigned short* __restrict__ wqr,
                             unsigned short* __restrict__ wpr)
{
    const int idx = blockIdx.x * 256 + threadIdx.x;
    if (idx < 540 * WK) {
        const int r = idx / WK, k = idx % WK;
        const int seg = r / 30, dd = r % 30;
        const int which = seg / 6, hh = seg % 6;
        float v = 0.f;
        if (k < 180)
            v = qkv_w[(which * 180 + hh * 30 + dd) * 180 + k];
        wqr[idx] = bf1(v);
    }
    const int j = idx - 540 * WK;
    if (j >= 0 && j < WK * WK) {
        const int r = j / WK, k = j % WK;
        float v = 0.f;
        if (r < 180 && k < 180)
            v = proj_w[r * 180 + k];
        wpr[j] = bf1(v);
    }
}

__global__ void __launch_bounds__(NT, 3)
waga_mfma(const float* __restrict__ x,
          const float* __restrict__ bpe,
          const unsigned short* __restrict__ wqr,
          const unsigned short* __restrict__ wpr,
          const float* __restrict__ qkv_b,
          const float* __restrict__ proj_b,
          const float* __restrict__ tau,
          float* __restrict__ out)
{
    extern __shared__ char smem[];
    unsigned short* xb   = (unsigned short*)(smem + OFF_XB);
    unsigned short* qk   = (unsigned short*)(smem + OFF_QK);
    unsigned short* vT   = (unsigned short*)(smem + OFF_VT);
    unsigned short* dBs  = (unsigned short*)(smem + OFF_DB);   // f16 bits
    float*          bpes = (float*)(smem + OFF_BPE);
    float*          qkvb = (float*)(smem + OFF_QKVB);

    const int b = blockIdx.x;
    const int t = threadIdx.x;
    const int w = t >> 6;      // wave 0..7
    const int l = t & 63;
    const int lr = l & 15;     // 16x16 lane row
    const int g  = l >> 4;     // 16x16 k-group
    const int r31 = l & 31;    // 32x32 lane row/col
    const int h5 = l >> 5;     // 32x32 lane half

    // att scratch: upper half of this window's out region (bytes 22528..46080)
    unsigned short* attg = (unsigned short*)((char*)out + (size_t)b * 46080 + 22528);

    // ================= phase 1: staging =================
    if (t < 192) {                       // xb pad cols 180..191
        const int n = t / 3, c = t % 3;
        *reinterpret_cast<uint2*>(xb + n * XB_P + 180 + 4 * c) = make_uint2(0u, 0u);
    } else if (t < 256) {                // attg pad cols 180..183
        const int n = t - 192;
        ushort4b z = {0, 0, 0, 0};
        *reinterpret_cast<ushort4b*>(attg + n * ATT_P + 180) = z;
    }
    {
        const float* xw = x + (size_t)b * 11520;
        for (int i = t; i < 64 * 45; i += NT) {
            const int n = i / 45, c4 = i % 45;
            const float4 v = *reinterpret_cast<const float4*>(xw + i * 4);
            *reinterpret_cast<uint2*>(xb + n * XB_P + c4 * 4) =
                make_uint2(bf2pk(v.x, v.y), bf2pk(v.z, v.w));
        }
    }
    if (t < 256) {                       // bpe -> LDS f32
        const float4 v = *reinterpret_cast<const float4*>(bpe + (size_t)b * 1024 + t * 4);
        *reinterpret_cast<float4*>(bpes + (t >> 2) * 20 + (t & 3) * 4) = v;
    }
    for (int i = t; i < 576; i += NT) {  // qkvb[seg*32+dd] (dd>=30 -> 0) — FULL coverage
        const int segp = i >> 5, dd = i & 31;
        const int which = segp / 6, hg = segp % 6;
        qkvb[i] = (dd < 30) ? qkv_b[which * 180 + hg * 30 + dd] : 0.f;
    }
    __syncthreads();

    // ================= phase 2a: dB (f16, full 64x64) =================
    {
        const int ti = t >> 4, tj = t & 15;   // rows {ti, ti+32}, cols {tj+16e}
        float acc0[4] = {0.f, 0.f, 0.f, 0.f};
        float acc1[4] = {0.f, 0.f, 0.f, 0.f};
        #pragma unroll
        for (int k4 = 0; k4 < 4; ++k4) {
            const float4 a0 = *reinterpret_cast<const float4*>(bpes + ti * 20 + 4 * k4);
            const float4 a1 = *reinterpret_cast<const float4*>(bpes + (ti + 32) * 20 + 4 * k4);
            #pragma unroll
            for (int e = 0; e < 4; ++e) {
                const float4 bb = *reinterpret_cast<const float4*>(bpes + (tj + 16 * e) * 20 + 4 * k4);
                float d;
                d = a0.x - bb.x; acc0[e] += d * d;
                d = a0.y - bb.y; acc0[e] += d * d;
                d = a0.z - bb.z; acc0[e] += d * d;
                d = a0.w - bb.w; acc0[e] += d * d;
                d = a1.x - bb.x; acc1[e] += d * d;
                d = a1.y - bb.y; acc1[e] += d * d;
                d = a1.z - bb.z; acc1[e] += d * d;
                d = a1.w - bb.w; acc1[e] += d * d;
            }
        }
        #pragma unroll
        for (int e = 0; e < 4; ++e) {
            dBs[ti * DB_P + tj + 16 * e] =
                __half_as_ushort(__float2half_rn(sqrtf(acc0[e])));
            dBs[(ti + 32) * DB_P + tj + 16 * e] =
                __half_as_ushort(__float2half_rn(sqrtf(acc1[e])));
        }
    }
    // no barrier: dB first read in attn, after the QKV barrier.

    // ================= passes: QKV (3 heads, 32x32 MFMA) + attention =================
    for (int pass = 0; pass < 2; ++pass) {
        if (pass) __syncthreads();       // attn(pass-1) done reading qk/vT

        // ---- QKV: 18 tiles = 9 segs x 2 tok-tiles; tile = seg*2+tt; wave keeps tt ----
        {
            const int tt = w & 1;
            const bool has2 = (w < 2);
            const bool aok = (r31 < 30);
            const unsigned short* xrow = xb + (tt * 32 + r31) * XB_P;
            int segp[3], which_[3], hh_[3];
            const unsigned short* arow[3];
            #pragma unroll
            for (int i = 0; i < 3; ++i) {
                const int tl = (w + 8 * i < 18) ? (w + 8 * i) : w;
                const int seg = tl >> 1;
                which_[i] = seg / 3; hh_[i] = seg % 3;
                segp[i] = which_[i] * 6 + 3 * pass + hh_[i];
                arow[i] = wqr + (size_t)(segp[i] * 30 + (aok ? r31 : 0)) * WK;
            }
            f32x16 acc[3];
            #pragma unroll
            for (int i = 0; i < 3; ++i)
                #pragma unroll
                for (int j = 0; j < 16; ++j) acc[i][j] = 0.f;
            const short8b zf = {0, 0, 0, 0, 0, 0, 0, 0};
            #pragma unroll
            for (int kk = 0; kk < 12; ++kk) {
                const short8b bfv = *reinterpret_cast<const short8b*>(xrow + kk * 16 + h5 * 8);
                const short8b a0 = aok ? *reinterpret_cast<const short8b*>(arow[0] + kk * 16 + h5 * 8) : zf;
                acc[0] = __builtin_amdgcn_mfma_f32_32x32x16_bf16(a0, bfv, acc[0], 0, 0, 0);
                const short8b a1 = aok ? *reinterpret_cast<const short8b*>(arow[1] + kk * 16 + h5 * 8) : zf;
                acc[1] = __builtin_amdgcn_mfma_f32_32x32x16_bf16(a1, bfv, acc[1], 0, 0, 0);
                if (has2) {
                    const short8b a2 = aok ? *reinterpret_cast<const short8b*>(arow[2] + kk * 16 + h5 * 8) : zf;
                    acc[2] = __builtin_amdgcn_mfma_f32_32x32x16_bf16(a2, bfv, acc[2], 0, 0, 0);
                }
            }
            // epilogue: lane owns tok = tt*32+r31, chans dd = 8q+4*h5+{0..3} per quad q
            const int tok = tt * 32 + r31;
            const int cperm = (tok & 32) + ((tok >> 2) & 3) * 8 + ((tok >> 4) & 1) * 4 + (tok & 3);
            #pragma unroll
            for (int i = 0; i < 3; ++i) {
                if (i == 2 && !has2) continue;
                const int wq_ = which_[i], hhv = hh_[i];
                #pragma unroll
                for (int q = 0; q < 4; ++q) {
                    const int db = 8 * q + 4 * h5;
                    const float4 bias = *reinterpret_cast<const float4*>(qkvb + segp[i] * 32 + db);
                    float v0 = acc[i][4 * q + 0] + bias.x;
                    float v1 = acc[i][4 * q + 1] + bias.y;
                    float v2 = acc[i][4 * q + 2] + bias.z;
                    float v3 = acc[i][4 * q + 3] + bias.w;
                    if (wq_ == 0) { v0 *= SCALE; v1 *= SCALE; v2 *= SCALE; v3 *= SCALE; }
                    if (wq_ < 2) {
                        *reinterpret_cast<uint2*>(qk + tok * QK_P + hhv * 64 + wq_ * 32 + db) =
                            make_uint2(bf2pk(v0, v1), bf2pk(v2, v3));
                    } else {
                        unsigned short* vb = vT + hhv * 2304 + db * VT_P + cperm;
                        vb[0 * VT_P] = bf1(v0);
                        vb[1 * VT_P] = bf1(v1);
                        vb[2 * VT_P] = bf1(v2);
                        vb[3 * VT_P] = bf1(v3);
                    }
                }
            }
        }
        __syncthreads();

        // ---- attention: 12 units (hh, mt) over 8 waves (16x16, proven) ----
        for (int u = w; u < 12; u += 8) {
            const int hh = u >> 2, mt = u & 3;
            const int h = 3 * pass + hh;
            const int tok = mt * 16 + lr;
            const unsigned short* qkh = qk + hh * 64;
            const short8b qf = *reinterpret_cast<const short8b*>(
                qkh + tok * QK_P + g * 8);
            short8b kf[4];
            #pragma unroll
            for (int jt = 0; jt < 4; ++jt)
                kf[jt] = *reinterpret_cast<const short8b*>(
                    qkh + (jt * 16 + lr) * QK_P + 32 + g * 8);
            short8b vf[2][2];
            #pragma unroll
            for (int ntd = 0; ntd < 2; ++ntd)
                #pragma unroll
                for (int ks = 0; ks < 2; ++ks)
                    vf[ntd][ks] = *reinterpret_cast<const short8b*>(
                        vT + hh * 2304 + (ntd * 16 + lr) * VT_P + ks * 32 + g * 8);
            const float itau = 1.f / fmaxf(tau[h], 1e-6f);
            f32x4 s[4];
            #pragma unroll
            for (int jt = 0; jt < 4; ++jt) {
                const ushort4b du = *reinterpret_cast<const ushort4b*>(
                    dBs + tok * DB_P + jt * 16 + g * 4);
                #pragma unroll
                for (int i = 0; i < 4; ++i)
                    s[jt][i] = -itau * __half2float(__ushort_as_half(du[i]));
            }
            __builtin_amdgcn_s_setprio(1);
            #pragma unroll
            for (int jt = 0; jt < 4; ++jt)
                s[jt] = __builtin_amdgcn_mfma_f32_16x16x32_bf16(kf[jt], qf, s[jt], 0, 0, 0);
            __builtin_amdgcn_s_setprio(0);
            float m4[4], a4[4];
            #pragma unroll
            for (int i = 0; i < 4; ++i)
                m4[i] = fmaxf(fmaxf(s[0][i], s[1][i]), fmaxf(s[2][i], s[3][i]));
            float mx = fmaxf(fmaxf(m4[0], m4[1]), fmaxf(m4[2], m4[3]));
            mx = fmaxf(mx, __shfl_xor(mx, 16));
            mx = fmaxf(mx, __shfl_xor(mx, 32));
            #pragma unroll
            for (int jt = 0; jt < 4; ++jt)
                #pragma unroll
                for (int i = 0; i < 4; ++i)
                    s[jt][i] = __expf(s[jt][i] - mx);
            #pragma unroll
            for (int i = 0; i < 4; ++i)
                a4[i] = (s[0][i] + s[1][i]) + (s[2][i] + s[3][i]);
            float sum = (a4[0] + a4[1]) + (a4[2] + a4[3]);
            sum += __shfl_xor(sum, 16);
            sum += __shfl_xor(sum, 32);
            const float inv = 1.f / sum;
            union { short8b v; unsigned int u[4]; } pb[2];
            #pragma unroll
            for (int ks = 0; ks < 2; ++ks) {
                pb[ks].u[0] = bf2pk(s[2 * ks][0] * inv, s[2 * ks][1] * inv);
                pb[ks].u[1] = bf2pk(s[2 * ks][2] * inv, s[2 * ks][3] * inv);
                pb[ks].u[2] = bf2pk(s[2 * ks + 1][0] * inv, s[2 * ks + 1][1] * inv);
                pb[ks].u[3] = bf2pk(s[2 * ks + 1][2] * inv, s[2 * ks + 1][3] * inv);
            }
            __builtin_amdgcn_s_setprio(1);
            f32x4 o0 = {0.f, 0.f, 0.f, 0.f}, o1 = {0.f, 0.f, 0.f, 0.f};
            o0 = __builtin_amdgcn_mfma_f32_16x16x32_bf16(vf[0][0], pb[0].v, o0, 0, 0, 0);
            o1 = __builtin_amdgcn_mfma_f32_16x16x32_bf16(vf[1][0], pb[0].v, o1, 0, 0, 0);
            o0 = __builtin_amdgcn_mfma_f32_16x16x32_bf16(vf[0][1], pb[1].v, o0, 0, 0, 0);
            o1 = __builtin_amdgcn_mfma_f32_16x16x32_bf16(vf[1][1], pb[1].v, o1, 0, 0, 0);
            __builtin_amdgcn_s_setprio(0);
            {
                const int col0 = h * 30 + g * 4;
                *reinterpret_cast<uint2*>(attg + tok * ATT_P + col0) =
                    make_uint2(bf2pk(o0[0], o0[1]), bf2pk(o0[2], o0[3]));
                const int col1 = h * 30 + 16 + g * 4;
                if (g < 3) {
                    *reinterpret_cast<uint2*>(attg + tok * ATT_P + col1) =
                        make_uint2(bf2pk(o1[0], o1[1]), bf2pk(o1[2], o1[3]));
                } else {
                    *reinterpret_cast<unsigned int*>(attg + tok * ATT_P + col1) =
                        bf2pk(o1[0], o1[1]);
                }
            }
        }
    }
    __syncthreads();   // all attg writes drained & visible

    // ================= proj: 12 tiles of [32 outchan][32 tok], 32x32 MFMA =================
    {
        const int tt = w & 1;
        const int tc0 = w >> 1;       // tile = w
        const int tc1 = tc0 + 4;      // tile = w+8
        const bool has1 = (w < 4);
        const unsigned short* brow = attg + (tt * 32 + r31) * ATT_P;
        f32x16 pa0, pa1;
        #pragma unroll
        for (int j = 0; j < 16; ++j) { pa0[j] = 0.f; pa1[j] = 0.f; }
        const short8b zf = {0, 0, 0, 0, 0, 0, 0, 0};
        #pragma unroll
        for (int kk = 0; kk < 12; ++kk) {
            const short8b bfv = (kk == 11 && h5 == 1) ? zf :
                *reinterpret_cast<const short8b*>(brow + kk * 16 + h5 * 8);
            const short8b a0 = *reinterpret_cast<const short8b*>(
                wpr + (size_t)(tc0 * 32 + r31) * WK + kk * 16 + h5 * 8);
            pa0 = __builtin_amdgcn_mfma_f32_32x32x16_bf16(a0, bfv, pa0, 0, 0, 0);
            if (has1) {
                const short8b a1 = *reinterpret_cast<const short8b*>(
                    wpr + (size_t)(tc1 * 32 + r31) * WK + kk * 16 + h5 * 8);
                pa1 = __builtin_amdgcn_mfma_f32_32x32x16_bf16(a1, bfv, pa1, 0, 0, 0);
            }
        }
        __syncthreads();   // all attg reads complete before out stores overwrite
        const int tok = tt * 32 + r31;
        float* orow = out + ((size_t)b * 64 + tok) * 180;
        #pragma unroll
        for (int q = 0; q < 4; ++q) {
            const int cb = tc0 * 32 + 8 * q + 4 * h5;
            if (cb <= 176) {
                const float4 pbv = *reinterpret_cast<const float4*>(proj_b + cb);
                *reinterpret_cast<float4*>(orow + cb) = make_float4(
                    pa0[4 * q + 0] + pbv.x, pa0[4 * q + 1] + pbv.y,
                    pa0[4 * q + 2] + pbv.z, pa0[4 * q + 3] + pbv.w);
            }
        }
        if (has1) {
            #pragma unroll
            for (int q = 0; q < 4; ++q) {
                const int cb = tc1 * 32 + 8 * q + 4 * h5;
                if (cb <= 176) {
                    const float4 pbv = *reinterpret_cast<const float4*>(proj_b + cb);
                    *reinterpret_cast<float4*>(orow + cb) = make_float4(
                        pa1[4 * q + 0] + pbv.x, pa1[4 * q + 1] + pbv.y,
                        pa1[4 * q + 2] + pbv.z, pa1[4 * q + 3] + pbv.w);
                }
            }
        }
    }
}

extern "C" void kernel_launch(void* const* d_in, const int* in_sizes, int n_in,
                              void* d_out, int out_size, void* d_ws, size_t ws_size,
                              hipStream_t stream) {
    (void)in_sizes; (void)n_in; (void)out_size; (void)ws_size;
    const float* x      = (const float*)d_in[0];
    const float* bpe    = (const float*)d_in[1];
    const float* qkv_w  = (const float*)d_in[2];
    const float* qkv_b  = (const float*)d_in[3];
    const float* proj_w = (const float*)d_in[4];
    const float* proj_b = (const float*)d_in[5];
    const float* tau    = (const float*)d_in[6];

    unsigned short* wqr = (unsigned short*)d_ws;     // 540*192 bf16 = 207360 B
    unsigned short* wpr = wqr + 540 * WK;            // 192*192 bf16 =  73728 B

    prep_weights<<<(540 * WK + WK * WK + 255) / 256, 256, 0, stream>>>(
        qkv_w, proj_w, wqr, wpr);

    (void)hipFuncSetAttribute((const void*)waga_mfma,
                              hipFuncAttributeMaxDynamicSharedMemorySize,
                              LDS_BYTES);
    waga_mfma<<<NWIN, NT, LDS_BYTES, stream>>>(x, bpe, wqr, wpr, qkv_b, proj_b, tau,
                                               (float*)d_out);
}

// Round 13
// 881.481 us; speedup vs baseline: 1.0178x; 1.0178x over previous
//
#include <hip/hip_runtime.h>
#include <hip/hip_fp16.h>
#include <hip/hip_bf16.h>
#include <math.h>

typedef __attribute__((ext_vector_type(8))) short short8b;    // 8 bf16 = 4 VGPR
typedef __attribute__((ext_vector_type(4))) float f32x4;      // 16x16 MFMA acc
typedef __attribute__((ext_vector_type(16))) float f32x16;    // 32x32 MFMA acc
typedef __attribute__((ext_vector_type(4))) unsigned short ushort4b;

#define NWIN 8192
#define NT   512
#define SCALE 0.18257418583505536f   // 30^-0.5

// ---- LDS geometry (element pitches) ----
#define XB_P 200    // xb [64][200] bf16; x cols 0..179 + pad 180..191 zero
#define QK_P 200    // qk [64][200] bf16 per pass: head hh: q @ hh*64, k @ hh*64+32 (pads auto-zero)
#define VT_P 72     // vT per head [32][72] bf16; rows 30,31 auto-zero; cols = permuted tok
#define DB_P 68     // dB [64][68] f16
#define ATT_P 184   // att in global (d_out upper half): [64][184] bf16, cols h*30+dd

// ---- LDS offsets (bytes) ----
#define OFF_XB   0                // 25600
#define OFF_QK   25600            // 25600
#define OFF_VT   51200            // 13824 (3 heads x 32*72*2)
#define OFF_DB   65024            // 8704
#define OFF_BPE  73728            // 5120  (bpe [64][20] f32)
#define OFF_QKVB 78848            // 2304  (qkvb [576] f32, seg*32+dd, dd>=30 -> 0)
#define LDS_BYTES 81152           // x2 = 162304 <= 163840 -> 2 blocks/CU

#define WK 192

__device__ __forceinline__ unsigned int bf2pk(float lo, float hi) {
    union { __hip_bfloat162 h; unsigned int u; } cv;
    cv.h = __float22bfloat162_rn(make_float2(lo, hi));
    return cv.u;
}
__device__ __forceinline__ unsigned short bf1(float v) {
    union { __hip_bfloat16 h; unsigned short u; } cv;
    cv.h = __float2bfloat16(v);
    return cv.u;
}

// wqr: [540][192] bf16. Row r = seg*30+dd, seg = which*6+hh_global, dd 0..29.
// wpr: [192][192] bf16 plain (pad rows/cols zero).
// d_ws total: 207360 + 73728 = 281088 B (proven-safe envelope).
__global__ void prep_weights(const float* __restrict__ qkv_w,
                             const float* __restrict__ proj_w,
                             unsigned short* __restrict__ wqr,
                             unsigned short* __restrict__ wpr)
{
    const int idx = blockIdx.x * 256 + threadIdx.x;
    if (idx < 540 * WK) {
        const int r = idx / WK, k = idx % WK;
        const int seg = r / 30, dd = r % 30;
        const int which = seg / 6, hh = seg % 6;
        float v = 0.f;
        if (k < 180)
            v = qkv_w[(which * 180 + hh * 30 + dd) * 180 + k];
        wqr[idx] = bf1(v);
    }
    const int j = idx - 540 * WK;
    if (j >= 0 && j < WK * WK) {
        const int r = j / WK, k = j % WK;
        float v = 0.f;
        if (r < 180 && k < 180)
            v = proj_w[r * 180 + k];
        wpr[j] = bf1(v);
    }
}

__global__ void __launch_bounds__(NT, 3)
waga_mfma(const float* __restrict__ x,
          const float* __restrict__ bpe,
          const unsigned short* __restrict__ wqr,
          const unsigned short* __restrict__ wpr,
          const float* __restrict__ qkv_b,
          const float* __restrict__ proj_b,
          const float* __restrict__ tau,
          float* __restrict__ out)
{
    extern __shared__ char smem[];
    unsigned short* xb   = (unsigned short*)(smem + OFF_XB);
    unsigned short* qk   = (unsigned short*)(smem + OFF_QK);
    unsigned short* vT   = (unsigned short*)(smem + OFF_VT);
    unsigned short* dBs  = (unsigned short*)(smem + OFF_DB);   // f16 bits
    float*          bpes = (float*)(smem + OFF_BPE);
    float*          qkvb = (float*)(smem + OFF_QKVB);

    const int b = blockIdx.x;
    const int t = threadIdx.x;
    const int w = t >> 6;      // wave 0..7
    const int l = t & 63;
    const int lr = l & 15;     // 16x16 lane row
    const int g  = l >> 4;     // 16x16 k-group
    const int r31 = l & 31;    // 32x32 lane row/col
    const int h5 = l >> 5;     // 32x32 lane half

    // att scratch: upper half of this window's out region (bytes 22528..46080)
    unsigned short* attg = (unsigned short*)((char*)out + (size_t)b * 46080 + 22528);

    // ================= phase 1: staging =================
    if (t < 192) {                       // xb pad cols 180..191
        const int n = t / 3, c = t % 3;
        *reinterpret_cast<uint2*>(xb + n * XB_P + 180 + 4 * c) = make_uint2(0u, 0u);
    } else if (t < 256) {                // attg pad cols 180..183
        const int n = t - 192;
        ushort4b z = {0, 0, 0, 0};
        *reinterpret_cast<ushort4b*>(attg + n * ATT_P + 180) = z;
    }
    {
        const float* xw = x + (size_t)b * 11520;
        for (int i = t; i < 64 * 45; i += NT) {
            const int n = i / 45, c4 = i % 45;
            const float4 v = *reinterpret_cast<const float4*>(xw + i * 4);
            *reinterpret_cast<uint2*>(xb + n * XB_P + c4 * 4) =
                make_uint2(bf2pk(v.x, v.y), bf2pk(v.z, v.w));
        }
    }
    if (t < 256) {                       // bpe -> LDS f32
        const float4 v = *reinterpret_cast<const float4*>(bpe + (size_t)b * 1024 + t * 4);
        *reinterpret_cast<float4*>(bpes + (t >> 2) * 20 + (t & 3) * 4) = v;
    }
    for (int i = t; i < 576; i += NT) {  // qkvb[seg*32+dd] (dd>=30 -> 0)
        const int segp = i >> 5, dd = i & 31;
        const int which = segp / 6, hg = segp % 6;
        qkvb[i] = (dd < 30) ? qkv_b[which * 180 + hg * 30 + dd] : 0.f;
    }
    __syncthreads();

    // ================= phase 2a: dB (f16, full 64x64) =================
    {
        const int ti = t >> 4, tj = t & 15;   // rows {ti, ti+32}, cols {tj+16e}
        float acc0[4] = {0.f, 0.f, 0.f, 0.f};
        float acc1[4] = {0.f, 0.f, 0.f, 0.f};
        #pragma unroll
        for (int k4 = 0; k4 < 4; ++k4) {
            const float4 a0 = *reinterpret_cast<const float4*>(bpes + ti * 20 + 4 * k4);
            const float4 a1 = *reinterpret_cast<const float4*>(bpes + (ti + 32) * 20 + 4 * k4);
            #pragma unroll
            for (int e = 0; e < 4; ++e) {
                const float4 bb = *reinterpret_cast<const float4*>(bpes + (tj + 16 * e) * 20 + 4 * k4);
                float d;
                d = a0.x - bb.x; acc0[e] += d * d;
                d = a0.y - bb.y; acc0[e] += d * d;
                d = a0.z - bb.z; acc0[e] += d * d;
                d = a0.w - bb.w; acc0[e] += d * d;
                d = a1.x - bb.x; acc1[e] += d * d;
                d = a1.y - bb.y; acc1[e] += d * d;
                d = a1.z - bb.z; acc1[e] += d * d;
                d = a1.w - bb.w; acc1[e] += d * d;
            }
        }
        #pragma unroll
        for (int e = 0; e < 4; ++e) {
            dBs[ti * DB_P + tj + 16 * e] =
                __half_as_ushort(__float2half_rn(sqrtf(acc0[e])));
            dBs[(ti + 32) * DB_P + tj + 16 * e] =
                __half_as_ushort(__float2half_rn(sqrtf(acc1[e])));
        }
    }
    // no barrier: dB first read in attn, after the QKV barrier.

    // ================= passes: QKV (3 heads, 32x32 MFMA) + attention =================
    for (int pass = 0; pass < 2; ++pass) {
        if (pass) __syncthreads();       // attn(pass-1) done reading qk/vT

        // ---- QKV: 18 tiles = 9 segs x 2 tok-tiles; tile = seg*2+tt; wave keeps tt ----
        {
            const int tt = w & 1;
            const bool has2 = (w < 2);
            const bool aok = (r31 < 30);
            const unsigned short* xrow = xb + (tt * 32 + r31) * XB_P;
            int segp[3], which_[3], hh_[3];
            const unsigned short* arow[3];
            #pragma unroll
            for (int i = 0; i < 3; ++i) {
                const int tl = (w + 8 * i < 18) ? (w + 8 * i) : w;
                const int seg = tl >> 1;
                which_[i] = seg / 3; hh_[i] = seg % 3;
                segp[i] = which_[i] * 6 + 3 * pass + hh_[i];
                arow[i] = wqr + (size_t)(segp[i] * 30 + (aok ? r31 : 0)) * WK;
            }
            f32x16 acc[3];
            #pragma unroll
            for (int i = 0; i < 3; ++i)
                #pragma unroll
                for (int j = 0; j < 16; ++j) acc[i][j] = 0.f;
            const short8b zf = {0, 0, 0, 0, 0, 0, 0, 0};
            #pragma unroll
            for (int kk = 0; kk < 12; ++kk) {
                const short8b bfv = *reinterpret_cast<const short8b*>(xrow + kk * 16 + h5 * 8);
                const short8b a0 = aok ? *reinterpret_cast<const short8b*>(arow[0] + kk * 16 + h5 * 8) : zf;
                acc[0] = __builtin_amdgcn_mfma_f32_32x32x16_bf16(a0, bfv, acc[0], 0, 0, 0);
                const short8b a1 = aok ? *reinterpret_cast<const short8b*>(arow[1] + kk * 16 + h5 * 8) : zf;
                acc[1] = __builtin_amdgcn_mfma_f32_32x32x16_bf16(a1, bfv, acc[1], 0, 0, 0);
                if (has2) {
                    const short8b a2 = aok ? *reinterpret_cast<const short8b*>(arow[2] + kk * 16 + h5 * 8) : zf;
                    acc[2] = __builtin_amdgcn_mfma_f32_32x32x16_bf16(a2, bfv, acc[2], 0, 0, 0);
                }
            }
            // epilogue: lane owns tok = tt*32+r31, chans dd = 8q+4*h5+{0..3} per quad q
            const int tok = tt * 32 + r31;
            const int cperm = (tok & 32) + ((tok >> 2) & 3) * 8 + ((tok >> 4) & 1) * 4 + (tok & 3);
            #pragma unroll
            for (int i = 0; i < 3; ++i) {
                if (i == 2 && !has2) continue;
                const int wq_ = which_[i], hhv = hh_[i];
                #pragma unroll
                for (int q = 0; q < 4; ++q) {
                    const int db = 8 * q + 4 * h5;
                    const float4 bias = *reinterpret_cast<const float4*>(qkvb + segp[i] * 32 + db);
                    float v0 = acc[i][4 * q + 0] + bias.x;
                    float v1 = acc[i][4 * q + 1] + bias.y;
                    float v2 = acc[i][4 * q + 2] + bias.z;
                    float v3 = acc[i][4 * q + 3] + bias.w;
                    if (wq_ == 0) { v0 *= SCALE; v1 *= SCALE; v2 *= SCALE; v3 *= SCALE; }
                    if (wq_ < 2) {
                        *reinterpret_cast<uint2*>(qk + tok * QK_P + hhv * 64 + wq_ * 32 + db) =
                            make_uint2(bf2pk(v0, v1), bf2pk(v2, v3));
                    } else {
                        unsigned short* vb = vT + hhv * 2304 + db * VT_P + cperm;
                        vb[0 * VT_P] = bf1(v0);
                        vb[1 * VT_P] = bf1(v1);
                        vb[2 * VT_P] = bf1(v2);
                        vb[3 * VT_P] = bf1(v3);
                    }
                }
            }
        }
        __syncthreads();

        // ---- attention: 12 units (hh, mt) over 8 waves (16x16, proven) ----
        for (int u = w; u < 12; u += 8) {
            const int hh = u >> 2, mt = u & 3;
            const int h = 3 * pass + hh;
            const int tok = mt * 16 + lr;
            const unsigned short* qkh = qk + hh * 64;
            const short8b qf = *reinterpret_cast<const short8b*>(
                qkh + tok * QK_P + g * 8);
            short8b kf[4];
            #pragma unroll
            for (int jt = 0; jt < 4; ++jt)
                kf[jt] = *reinterpret_cast<const short8b*>(
                    qkh + (jt * 16 + lr) * QK_P + 32 + g * 8);
            short8b vf[2][2];
            #pragma unroll
            for (int ntd = 0; ntd < 2; ++ntd)
                #pragma unroll
                for (int ks = 0; ks < 2; ++ks)
                    vf[ntd][ks] = *reinterpret_cast<const short8b*>(
                        vT + hh * 2304 + (ntd * 16 + lr) * VT_P + ks * 32 + g * 8);
            const float itau = 1.f / fmaxf(tau[h], 1e-6f);
            f32x4 s[4];
            #pragma unroll
            for (int jt = 0; jt < 4; ++jt) {
                const ushort4b du = *reinterpret_cast<const ushort4b*>(
                    dBs + tok * DB_P + jt * 16 + g * 4);
                #pragma unroll
                for (int i = 0; i < 4; ++i)
                    s[jt][i] = -itau * __half2float(__ushort_as_half(du[i]));
            }
            __builtin_amdgcn_s_setprio(1);
            #pragma unroll
            for (int jt = 0; jt < 4; ++jt)
                s[jt] = __builtin_amdgcn_mfma_f32_16x16x32_bf16(kf[jt], qf, s[jt], 0, 0, 0);
            __builtin_amdgcn_s_setprio(0);
            float m4[4], a4[4];
            #pragma unroll
            for (int i = 0; i < 4; ++i)
                m4[i] = fmaxf(fmaxf(s[0][i], s[1][i]), fmaxf(s[2][i], s[3][i]));
            float mx = fmaxf(fmaxf(m4[0], m4[1]), fmaxf(m4[2], m4[3]));
            mx = fmaxf(mx, __shfl_xor(mx, 16));
            mx = fmaxf(mx, __shfl_xor(mx, 32));
            #pragma unroll
            for (int jt = 0; jt < 4; ++jt)
                #pragma unroll
                for (int i = 0; i < 4; ++i)
                    s[jt][i] = __expf(s[jt][i] - mx);
            #pragma unroll
            for (int i = 0; i < 4; ++i)
                a4[i] = (s[0][i] + s[1][i]) + (s[2][i] + s[3][i]);
            float sum = (a4[0] + a4[1]) + (a4[2] + a4[3]);
            sum += __shfl_xor(sum, 16);
            sum += __shfl_xor(sum, 32);
            const float inv = 1.f / sum;
            union { short8b v; unsigned int u[4]; } pb[2];
            #pragma unroll
            for (int ks = 0; ks < 2; ++ks) {
                pb[ks].u[0] = bf2pk(s[2 * ks][0] * inv, s[2 * ks][1] * inv);
                pb[ks].u[1] = bf2pk(s[2 * ks][2] * inv, s[2 * ks][3] * inv);
                pb[ks].u[2] = bf2pk(s[2 * ks + 1][0] * inv, s[2 * ks + 1][1] * inv);
                pb[ks].u[3] = bf2pk(s[2 * ks + 1][2] * inv, s[2 * ks + 1][3] * inv);
            }
            __builtin_amdgcn_s_setprio(1);
            f32x4 o0 = {0.f, 0.f, 0.f, 0.f}, o1 = {0.f, 0.f, 0.f, 0.f};
            o0 = __builtin_amdgcn_mfma_f32_16x16x32_bf16(vf[0][0], pb[0].v, o0, 0, 0, 0);
            o1 = __builtin_amdgcn_mfma_f32_16x16x32_bf16(vf[1][0], pb[0].v, o1, 0, 0, 0);
            o0 = __builtin_amdgcn_mfma_f32_16x16x32_bf16(vf[0][1], pb[1].v, o0, 0, 0, 0);
            o1 = __builtin_amdgcn_mfma_f32_16x16x32_bf16(vf[1][1], pb[1].v, o1, 0, 0, 0);
            __builtin_amdgcn_s_setprio(0);
            {
                const int col0 = h * 30 + g * 4;
                *reinterpret_cast<uint2*>(attg + tok * ATT_P + col0) =
                    make_uint2(bf2pk(o0[0], o0[1]), bf2pk(o0[2], o0[3]));
                const int col1 = h * 30 + 16 + g * 4;
                if (g < 3) {
                    *reinterpret_cast<uint2*>(attg + tok * ATT_P + col1) =
                        make_uint2(bf2pk(o1[0], o1[1]), bf2pk(o1[2], o1[3]));
                } else {
                    *reinterpret_cast<unsigned int*>(attg + tok * ATT_P + col1) =
                        bf2pk(o1[0], o1[1]);
                }
            }
        }
    }
    __syncthreads();   // all attg writes drained & visible

    // ================= proj: D[out-chan][tok], 16x16, 6 tiles/wave (R10-proven) =================
    {
        const int mt = w & 3;                 // wave's token group
        const int ntb = (w >> 2) * 6;         // nt = ntb..ntb+5
        short8b attf[6];
        #pragma unroll
        for (int kk = 0; kk < 6; ++kk) {
            if (kk == 5 && g == 3)            // att cols 184..191 don't exist
                attf[kk] = short8b{0, 0, 0, 0, 0, 0, 0, 0};
            else
                attf[kk] = *reinterpret_cast<const short8b*>(
                    attg + (mt * 16 + lr) * ATT_P + kk * 32 + g * 8);
        }
        f32x4 pacc[6];
        short8b wf[6];
        #pragma unroll
        for (int kk = 0; kk < 6; ++kk)
            wf[kk] = *reinterpret_cast<const short8b*>(
                wpr + (size_t)(ntb * 16 + lr) * WK + kk * 32 + g * 8);
        #pragma unroll
        for (int q6 = 0; q6 < 6; ++q6) {
            short8b wcur[6];
            #pragma unroll
            for (int kk = 0; kk < 6; ++kk) wcur[kk] = wf[kk];
            if (q6 < 5) {                     // prefetch next tile's weights
                const unsigned short* wrown =
                    wpr + (size_t)((ntb + q6 + 1) * 16 + lr) * WK;
                #pragma unroll
                for (int kk = 0; kk < 6; ++kk)
                    wf[kk] = *reinterpret_cast<const short8b*>(wrown + kk * 32 + g * 8);
            }
            const int cb = (ntb + q6) * 16 + g * 4;
            f32x4 acc;
            #pragma unroll
            for (int i = 0; i < 4; ++i)
                acc[i] = (cb + i < 180) ? proj_b[cb + i] : 0.f;
            #pragma unroll
            for (int kk = 0; kk < 6; ++kk)
                acc = __builtin_amdgcn_mfma_f32_16x16x32_bf16(wcur[kk], attf[kk], acc, 0, 0, 0);
            pacc[q6] = acc;
        }
        __syncthreads();   // all attg reads complete before out stores overwrite
        #pragma unroll
        for (int q6 = 0; q6 < 6; ++q6) {
            const int cb = (ntb + q6) * 16 + g * 4;
            if (cb < 177) {
                const int tok = mt * 16 + lr;
                *reinterpret_cast<float4*>(out + ((size_t)b * 64 + tok) * 180 + cb) =
                    make_float4(pacc[q6][0], pacc[q6][1], pacc[q6][2], pacc[q6][3]);
            }
        }
    }
}

extern "C" void kernel_launch(void* const* d_in, const int* in_sizes, int n_in,
                              void* d_out, int out_size, void* d_ws, size_t ws_size,
                              hipStream_t stream) {
    (void)in_sizes; (void)n_in; (void)out_size; (void)ws_size;
    const float* x      = (const float*)d_in[0];
    const float* bpe    = (const float*)d_in[1];
    const float* qkv_w  = (const float*)d_in[2];
    const float* qkv_b  = (const float*)d_in[3];
    const float* proj_w = (const float*)d_in[4];
    const float* proj_b = (const float*)d_in[5];
    const float* tau    = (const float*)d_in[6];

    unsigned short* wqr = (unsigned short*)d_ws;     // 540*192 bf16 = 207360 B
    unsigned short* wpr = wqr + 540 * WK;            // 192*192 bf16 =  73728 B

    prep_weights<<<(540 * WK + WK * WK + 255) / 256, 256, 0, stream>>>(
        qkv_w, proj_w, wqr, wpr);

    (void)hipFuncSetAttribute((const void*)waga_mfma,
                              hipFuncAttributeMaxDynamicSharedMemorySize,
                              LDS_BYTES);
    waga_mfma<<<NWIN, NT, LDS_BYTES, stream>>>(x, bpe, wqr, wpr, qkv_b, proj_b, tau,
                                               (float*)d_out);
}

// Round 14
// 747.696 us; speedup vs baseline: 1.1999x; 1.1789x over previous
//
#include <hip/hip_runtime.h>
#include <hip/hip_fp16.h>
#include <hip/hip_bf16.h>
#include <math.h>

typedef __attribute__((ext_vector_type(8))) short short8b;   // 8 bf16 = 4 VGPR
typedef __attribute__((ext_vector_type(4))) float f32x4;     // MFMA acc
typedef __attribute__((ext_vector_type(4))) unsigned short ushort4b;

#define NWIN 8192
#define NT   512
#define SCALE 0.18257418583505536f   // 30^-0.5

// ---- LDS geometry ----
#define XB_P 200      // xb [64][200] bf16; cols 0..179 + pad 180..191 zero
#define QKB_P 72      // qk buf [64][72] bf16: q @0..29, k @32..61 (pads auto-zero)
#define VT_P 72       // vT buf [32][72] bf16; rows 30,31 auto-zero; cols = permuted tok
#define DB_P 68       // dB [64][68] f16
#define ATT_P 184     // att in global (d_out upper half)
#define QKB_SZ (64 * QKB_P)   // 4608 shorts = 9216 B
#define VTB_SZ (32 * VT_P)    // 2304 shorts = 4608 B

// ---- LDS offsets (bytes) ----
#define OFF_XB  0                 // 25600
#define OFF_QKB 25600             // 2 x 9216 = 18432
#define OFF_VTB 44032             // 2 x 4608 = 9216
#define OFF_DB  53248             // 8704
#define OFF_BPE 61952             // 5120
#define LDS_BYTES 67072           // x2 = 134144 <= 163840 -> 2 blocks/CU

#define WK 192

__device__ __forceinline__ unsigned int bf2pk(float lo, float hi) {
    union { __hip_bfloat162 h; unsigned int u; } cv;
    cv.h = __float22bfloat162_rn(make_float2(lo, hi));
    return cv.u;
}
__device__ __forceinline__ unsigned short bf1(float v) {
    union { __hip_bfloat16 h; unsigned short u; } cv;
    cv.h = __float2bfloat16(v);
    return cv.u;
}

// wqr: [540][192] bf16. Row r = seg*30+dd, seg = which*6+h, dd 0..29. (R7/R8-proven)
// wpr: [192][192] bf16 plain (pad rows/cols zero).
// d_ws total: 207360 + 73728 = 281088 B (proven-safe envelope).
__global__ void prep_weights(const float* __restrict__ qkv_w,
                             const float* __restrict__ proj_w,
                             unsigned short* __restrict__ wqr,
                             unsigned short* __restrict__ wpr)
{
    const int idx = blockIdx.x * 256 + threadIdx.x;
    if (idx < 540 * WK) {
        const int r = idx / WK, k = idx % WK;
        const int seg = r / 30, dd = r % 30;
        const int which = seg / 6, hh = seg % 6;
        float v = 0.f;
        if (k < 180)
            v = qkv_w[(which * 180 + hh * 30 + dd) * 180 + k];
        wqr[idx] = bf1(v);
    }
    const int j = idx - 540 * WK;
    if (j >= 0 && j < WK * WK) {
        const int r = j / WK, k = j % WK;
        float v = 0.f;
        if (r < 180 && k < 180)
            v = proj_w[r * 180 + k];
        wpr[j] = bf1(v);
    }
}

__global__ void __launch_bounds__(NT, 4)
waga_mfma(const float* __restrict__ x,
          const float* __restrict__ bpe,
          const unsigned short* __restrict__ wqr,
          const unsigned short* __restrict__ wpr,
          const float* __restrict__ qkv_b,
          const float* __restrict__ proj_b,
          const float* __restrict__ tau,
          float* __restrict__ out)
{
    extern __shared__ char smem[];
    unsigned short* xb    = (unsigned short*)(smem + OFF_XB);
    unsigned short* qkbuf = (unsigned short*)(smem + OFF_QKB);  // [2][64][72]
    unsigned short* vTbuf = (unsigned short*)(smem + OFF_VTB);  // [2][32][72]
    unsigned short* dBs   = (unsigned short*)(smem + OFF_DB);   // f16 bits
    float*          bpes  = (float*)(smem + OFF_BPE);

    const int b = blockIdx.x;
    const int t = threadIdx.x;
    const int w = t >> 6;      // wave 0..7
    const int l = t & 63;
    const int lr = l & 15;
    const int g  = l >> 4;

    // att scratch: upper half of this window's out region (bytes 22528..46080)
    unsigned short* attg = (unsigned short*)((char*)out + (size_t)b * 46080 + 22528);

    // ================= phase 1: staging (R8-proven) =================
    if (t < 192) {                       // xb pad cols 180..191
        const int n = t / 3, c = t % 3;
        *reinterpret_cast<uint2*>(xb + n * XB_P + 180 + 4 * c) = make_uint2(0u, 0u);
    } else if (t < 256) {                // attg pad cols 180..183
        const int n = t - 192;
        ushort4b z = {0, 0, 0, 0};
        *reinterpret_cast<ushort4b*>(attg + n * ATT_P + 180) = z;
    }
    {
        const float* xw = x + (size_t)b * 11520;
        for (int i = t; i < 64 * 45; i += NT) {
            const int n = i / 45, c4 = i % 45;
            const float4 v = *reinterpret_cast<const float4*>(xw + i * 4);
            *reinterpret_cast<uint2*>(xb + n * XB_P + c4 * 4) =
                make_uint2(bf2pk(v.x, v.y), bf2pk(v.z, v.w));
        }
    }
    if (t < 256) {                       // bpe -> LDS f32
        const float4 v = *reinterpret_cast<const float4*>(bpe + (size_t)b * 1024 + t * 4);
        *reinterpret_cast<float4*>(bpes + (t >> 2) * 20 + (t & 3) * 4) = v;
    }
    __syncthreads();

    // ================= phase 2a: dB (f16, full 64x64, R8-proven) =================
    {
        const int ti = t >> 4, tj = t & 15;
        float acc0[4] = {0.f, 0.f, 0.f, 0.f};
        float acc1[4] = {0.f, 0.f, 0.f, 0.f};
        #pragma unroll
        for (int k4 = 0; k4 < 4; ++k4) {
            const float4 a0 = *reinterpret_cast<const float4*>(bpes + ti * 20 + 4 * k4);
            const float4 a1 = *reinterpret_cast<const float4*>(bpes + (ti + 32) * 20 + 4 * k4);
            #pragma unroll
            for (int e = 0; e < 4; ++e) {
                const float4 bb = *reinterpret_cast<const float4*>(bpes + (tj + 16 * e) * 20 + 4 * k4);
                float d;
                d = a0.x - bb.x; acc0[e] += d * d;
                d = a0.y - bb.y; acc0[e] += d * d;
                d = a0.z - bb.z; acc0[e] += d * d;
                d = a0.w - bb.w; acc0[e] += d * d;
                d = a1.x - bb.x; acc1[e] += d * d;
                d = a1.y - bb.y; acc1[e] += d * d;
                d = a1.z - bb.z; acc1[e] += d * d;
                d = a1.w - bb.w; acc1[e] += d * d;
            }
        }
        #pragma unroll
        for (int e = 0; e < 4; ++e) {
            dBs[ti * DB_P + tj + 16 * e] =
                __half_as_ushort(__float2half_rn(sqrtf(acc0[e])));
            dBs[(ti + 32) * DB_P + tj + 16 * e] =
                __half_as_ushort(__float2half_rn(sqrtf(acc1[e])));
        }
    }
    // no barrier: dB first read in attn, after >=1 barrier.

    // ---- lambdas: single-head QKV tile (waves 0-5) and attn unit (waves 4-7) ----
    auto qkv_head = [&](int hg, int bufp) {
        if (w >= 6) return;
        const int which = w >> 1, half = w & 1;   // tile = which*2+half
        const int ddr = half * 16 + lr;
        const bool aok = (ddr < 30);
        const unsigned short* wrow =
            wqr + (size_t)((which * 6 + hg) * 30 + (aok ? ddr : 0)) * WK;
        const short8b zf = {0, 0, 0, 0, 0, 0, 0, 0};
        short8b wf[6];
        #pragma unroll
        for (int kk = 0; kk < 6; ++kk)
            wf[kk] = aok ? *reinterpret_cast<const short8b*>(wrow + kk * 32 + g * 8) : zf;
        const int ddb = half * 16 + g * 4;
        const int cbase = which * 180 + hg * 30;
        f32x4 binit;
        #pragma unroll
        for (int i = 0; i < 4; ++i)
            binit[i] = (ddb + i < 30) ? qkv_b[cbase + ddb + i] : 0.f;
        f32x4 acc[4] = {binit, binit, binit, binit};
        #pragma unroll
        for (int kk = 0; kk < 6; ++kk) {
            #pragma unroll
            for (int mt = 0; mt < 4; ++mt) {
                const short8b xf = *reinterpret_cast<const short8b*>(
                    xb + (mt * 16 + lr) * XB_P + kk * 32 + g * 8);
                acc[mt] = __builtin_amdgcn_mfma_f32_16x16x32_bf16(wf[kk], xf, acc[mt], 0, 0, 0);
            }
        }
        unsigned short* qkb = qkbuf + bufp * QKB_SZ;
        unsigned short* vtb = vTbuf + bufp * VTB_SZ;
        #pragma unroll
        for (int mt = 0; mt < 4; ++mt) {
            const int tok = mt * 16 + lr;
            float v0 = acc[mt][0], v1 = acc[mt][1], v2 = acc[mt][2], v3 = acc[mt][3];
            if (which == 0) { v0 *= SCALE; v1 *= SCALE; v2 *= SCALE; v3 *= SCALE; }
            if (which < 2) {
                *reinterpret_cast<uint2*>(qkb + tok * QKB_P + which * 32 + ddb) =
                    make_uint2(bf2pk(v0, v1), bf2pk(v2, v3));
            } else {
                const int c = (tok & 32) + ((tok >> 2) & 3) * 8 + ((tok >> 4) & 1) * 4 + (tok & 3);
                unsigned short* vb = vtb + ddb * VT_P + c;
                vb[0 * VT_P] = bf1(v0);
                vb[1 * VT_P] = bf1(v1);
                vb[2 * VT_P] = bf1(v2);
                vb[3 * VT_P] = bf1(v3);
            }
        }
    };

    auto attn_head = [&](int h, int bufp) {
        if (w < 4) return;
        const int mt = w - 4;
        const int tok = mt * 16 + lr;
        const unsigned short* qkb = qkbuf + bufp * QKB_SZ;
        const unsigned short* vtb = vTbuf + bufp * VTB_SZ;
        const short8b qf = *reinterpret_cast<const short8b*>(qkb + tok * QKB_P + g * 8);
        short8b kf[4];
        #pragma unroll
        for (int jt = 0; jt < 4; ++jt)
            kf[jt] = *reinterpret_cast<const short8b*>(
                qkb + (jt * 16 + lr) * QKB_P + 32 + g * 8);
        short8b vf[2][2];
        #pragma unroll
        for (int ntd = 0; ntd < 2; ++ntd)
            #pragma unroll
            for (int ks = 0; ks < 2; ++ks)
                vf[ntd][ks] = *reinterpret_cast<const short8b*>(
                    vtb + (ntd * 16 + lr) * VT_P + ks * 32 + g * 8);
        const float itau = 1.f / fmaxf(tau[h], 1e-6f);
        f32x4 s[4];
        #pragma unroll
        for (int jt = 0; jt < 4; ++jt) {
            const ushort4b du = *reinterpret_cast<const ushort4b*>(
                dBs + tok * DB_P + jt * 16 + g * 4);
            #pragma unroll
            for (int i = 0; i < 4; ++i)
                s[jt][i] = -itau * __half2float(__ushort_as_half(du[i]));
        }
        #pragma unroll
        for (int jt = 0; jt < 4; ++jt)
            s[jt] = __builtin_amdgcn_mfma_f32_16x16x32_bf16(kf[jt], qf, s[jt], 0, 0, 0);
        float m4[4], a4[4];
        #pragma unroll
        for (int i = 0; i < 4; ++i)
            m4[i] = fmaxf(fmaxf(s[0][i], s[1][i]), fmaxf(s[2][i], s[3][i]));
        float mx = fmaxf(fmaxf(m4[0], m4[1]), fmaxf(m4[2], m4[3]));
        mx = fmaxf(mx, __shfl_xor(mx, 16));
        mx = fmaxf(mx, __shfl_xor(mx, 32));
        #pragma unroll
        for (int jt = 0; jt < 4; ++jt)
            #pragma unroll
            for (int i = 0; i < 4; ++i)
                s[jt][i] = __expf(s[jt][i] - mx);
        #pragma unroll
        for (int i = 0; i < 4; ++i)
            a4[i] = (s[0][i] + s[1][i]) + (s[2][i] + s[3][i]);
        float sum = (a4[0] + a4[1]) + (a4[2] + a4[3]);
        sum += __shfl_xor(sum, 16);
        sum += __shfl_xor(sum, 32);
        const float inv = 1.f / sum;
        union { short8b v; unsigned int u[4]; } pb[2];
        #pragma unroll
        for (int ks = 0; ks < 2; ++ks) {
            pb[ks].u[0] = bf2pk(s[2 * ks][0] * inv, s[2 * ks][1] * inv);
            pb[ks].u[1] = bf2pk(s[2 * ks][2] * inv, s[2 * ks][3] * inv);
            pb[ks].u[2] = bf2pk(s[2 * ks + 1][0] * inv, s[2 * ks + 1][1] * inv);
            pb[ks].u[3] = bf2pk(s[2 * ks + 1][2] * inv, s[2 * ks + 1][3] * inv);
        }
        f32x4 o0 = {0.f, 0.f, 0.f, 0.f}, o1 = {0.f, 0.f, 0.f, 0.f};
        o0 = __builtin_amdgcn_mfma_f32_16x16x32_bf16(vf[0][0], pb[0].v, o0, 0, 0, 0);
        o1 = __builtin_amdgcn_mfma_f32_16x16x32_bf16(vf[1][0], pb[0].v, o1, 0, 0, 0);
        o0 = __builtin_amdgcn_mfma_f32_16x16x32_bf16(vf[0][1], pb[1].v, o0, 0, 0, 0);
        o1 = __builtin_amdgcn_mfma_f32_16x16x32_bf16(vf[1][1], pb[1].v, o1, 0, 0, 0);
        {
            const int col0 = h * 30 + g * 4;
            *reinterpret_cast<uint2*>(attg + tok * ATT_P + col0) =
                make_uint2(bf2pk(o0[0], o0[1]), bf2pk(o0[2], o0[3]));
            const int col1 = h * 30 + 16 + g * 4;
            if (g < 3) {
                *reinterpret_cast<uint2*>(attg + tok * ATT_P + col1) =
                    make_uint2(bf2pk(o1[0], o1[1]), bf2pk(o1[2], o1[3]));
            } else {   // dd 28,29 only
                *reinterpret_cast<unsigned int*>(attg + tok * ATT_P + col1) =
                    bf2pk(o1[0], o1[1]);
            }
        }
    };

    // ================= merged pipeline: QKV(h+1) || attn(h) =================
    qkv_head(0, 0);
    __syncthreads();
    for (int h = 0; h < 6; ++h) {
        if (h < 5) qkv_head(h + 1, (h + 1) & 1);   // waves 0-5, writes buf (h+1)&1
        attn_head(h, h & 1);                        // waves 4-7, reads buf h&1
        __syncthreads();
    }

    // ================= proj: D[out-chan][tok], 16x16, 6 tiles/wave (R10-proven) =================
    {
        const int mt = w & 3;                 // wave's token group
        const int ntb = (w >> 2) * 6;         // nt = ntb..ntb+5
        short8b attf[6];
        #pragma unroll
        for (int kk = 0; kk < 6; ++kk) {
            if (kk == 5 && g == 3)            // att cols 184..191 don't exist
                attf[kk] = short8b{0, 0, 0, 0, 0, 0, 0, 0};
            else
                attf[kk] = *reinterpret_cast<const short8b*>(
                    attg + (mt * 16 + lr) * ATT_P + kk * 32 + g * 8);
        }
        f32x4 pacc[6];
        short8b wf[6];
        #pragma unroll
        for (int kk = 0; kk < 6; ++kk)
            wf[kk] = *reinterpret_cast<const short8b*>(
                wpr + (size_t)(ntb * 16 + lr) * WK + kk * 32 + g * 8);
        #pragma unroll
        for (int q6 = 0; q6 < 6; ++q6) {
            short8b wcur[6];
            #pragma unroll
            for (int kk = 0; kk < 6; ++kk) wcur[kk] = wf[kk];
            if (q6 < 5) {                     // prefetch next tile's weights
                const unsigned short* wrown =
                    wpr + (size_t)((ntb + q6 + 1) * 16 + lr) * WK;
                #pragma unroll
                for (int kk = 0; kk < 6; ++kk)
                    wf[kk] = *reinterpret_cast<const short8b*>(wrown + kk * 32 + g * 8);
            }
            const int cb = (ntb + q6) * 16 + g * 4;
            f32x4 acc;
            #pragma unroll
            for (int i = 0; i < 4; ++i)
                acc[i] = (cb + i < 180) ? proj_b[cb + i] : 0.f;
            #pragma unroll
            for (int kk = 0; kk < 6; ++kk)
                acc = __builtin_amdgcn_mfma_f32_16x16x32_bf16(wcur[kk], attf[kk], acc, 0, 0, 0);
            pacc[q6] = acc;
        }
        __syncthreads();   // all attg reads complete before out stores overwrite
        #pragma unroll
        for (int q6 = 0; q6 < 6; ++q6) {
            const int cb = (ntb + q6) * 16 + g * 4;
            if (cb < 177) {
                const int tok = mt * 16 + lr;
                *reinterpret_cast<float4*>(out + ((size_t)b * 64 + tok) * 180 + cb) =
                    make_float4(pacc[q6][0], pacc[q6][1], pacc[q6][2], pacc[q6][3]);
            }
        }
    }
}

extern "C" void kernel_launch(void* const* d_in, const int* in_sizes, int n_in,
                              void* d_out, int out_size, void* d_ws, size_t ws_size,
                              hipStream_t stream) {
    (void)in_sizes; (void)n_in; (void)out_size; (void)ws_size;
    const float* x      = (const float*)d_in[0];
    const float* bpe    = (const float*)d_in[1];
    const float* qkv_w  = (const float*)d_in[2];
    const float* qkv_b  = (const float*)d_in[3];
    const float* proj_w = (const float*)d_in[4];
    const float* proj_b = (const float*)d_in[5];
    const float* tau    = (const float*)d_in[6];

    unsigned short* wqr = (unsigned short*)d_ws;     // 540*192 bf16 = 207360 B
    unsigned short* wpr = wqr + 540 * WK;            // 192*192 bf16 =  73728 B

    prep_weights<<<(540 * WK + WK * WK + 255) / 256, 256, 0, stream>>>(
        qkv_w, proj_w, wqr, wpr);

    (void)hipFuncSetAttribute((const void*)waga_mfma,
                              hipFuncAttributeMaxDynamicSharedMemorySize,
                              LDS_BYTES);
    waga_mfma<<<NWIN, NT, LDS_BYTES, stream>>>(x, bpe, wqr, wpr, qkv_b, proj_b, tau,
                                               (float*)d_out);
}

// Round 15
// 724.939 us; speedup vs baseline: 1.2375x; 1.0314x over previous
//
#include <hip/hip_runtime.h>
#include <hip/hip_fp16.h>
#include <hip/hip_bf16.h>
#include <math.h>

typedef __attribute__((ext_vector_type(8))) short short8b;   // 8 bf16 = 4 VGPR
typedef __attribute__((ext_vector_type(4))) float f32x4;     // MFMA acc
typedef __attribute__((ext_vector_type(4))) unsigned short ushort4b;

#define NWIN 8192
#define NT   512
#define SCALE 0.18257418583505536f   // 30^-0.5

// ---- LDS geometry (element pitches) ----
#define XB_P 200    // xb [64][200] bf16; x cols 0..179 + pad 180..191 zero
#define QK_P 200    // qk [64][200] bf16 per pass: head hh: q @ hh*64, k @ hh*64+32 (pads auto-zero)
#define VT_P 72     // vT per head [32][72] bf16; rows 30,31 auto-zero; cols = permuted tok
#define DB_P 68     // dB [64][68] f16
#define ATT_P 184   // att in global (d_out upper half): [64][184] bf16, cols h*30+dd

// ---- LDS offsets (bytes) ----
#define OFF_XB  0                 // 25600
#define OFF_QK  25600             // 25600
#define OFF_VT  51200             // 13824 (3 heads x 32*72*2)
#define OFF_DB  65024             // 8704
#define OFF_BPE 73728             // 5120  (bpe [64][20] f32)
#define LDS_BYTES 78848           // 77 KB -> 2 blocks/CU

#define WK 192

__device__ __forceinline__ unsigned int bf2pk(float lo, float hi) {
    union { __hip_bfloat162 h; unsigned int u; } cv;
    cv.h = __float22bfloat162_rn(make_float2(lo, hi));
    return cv.u;
}
__device__ __forceinline__ unsigned short bf1(float v) {
    union { __hip_bfloat16 h; unsigned short u; } cv;
    cv.h = __float2bfloat16(v);
    return cv.u;
}

// wqr: [540][192] bf16. Row r = seg*30+dd, seg = which*6+hh_global, dd 0..29.
// wpr: [192][192] bf16 plain (pad rows/cols zero).
// d_ws total: 207360 + 73728 = 281088 B (proven-safe envelope).
__global__ void prep_weights(const float* __restrict__ qkv_w,
                             const float* __restrict__ proj_w,
                             unsigned short* __restrict__ wqr,
                             unsigned short* __restrict__ wpr)
{
    const int idx = blockIdx.x * 256 + threadIdx.x;
    if (idx < 540 * WK) {
        const int r = idx / WK, k = idx % WK;
        const int seg = r / 30, dd = r % 30;
        const int which = seg / 6, hh = seg % 6;
        float v = 0.f;
        if (k < 180)
            v = qkv_w[(which * 180 + hh * 30 + dd) * 180 + k];
        wqr[idx] = bf1(v);
    }
    const int j = idx - 540 * WK;
    if (j >= 0 && j < WK * WK) {
        const int r = j / WK, k = j % WK;
        float v = 0.f;
        if (r < 180 && k < 180)
            v = proj_w[r * 180 + k];
        wpr[j] = bf1(v);
    }
}

__global__ void __launch_bounds__(NT, 4)
waga_mfma(const float* __restrict__ x,
          const float* __restrict__ bpe,
          const unsigned short* __restrict__ wqr,
          const unsigned short* __restrict__ wpr,
          const float* __restrict__ qkv_b,
          const float* __restrict__ proj_b,
          const float* __restrict__ tau,
          float* __restrict__ out)
{
    extern __shared__ char smem[];
    unsigned short* xb   = (unsigned short*)(smem + OFF_XB);
    unsigned short* qk   = (unsigned short*)(smem + OFF_QK);
    unsigned short* vT   = (unsigned short*)(smem + OFF_VT);
    unsigned short* dBs  = (unsigned short*)(smem + OFF_DB);   // f16 bits
    float*          bpes = (float*)(smem + OFF_BPE);

    const int b = blockIdx.x;
    const int t = threadIdx.x;
    const int w = t >> 6;      // wave 0..7
    const int l = t & 63;
    const int lr = l & 15;
    const int g  = l >> 4;

    // att scratch: upper half of this window's out region (bytes 22528..46080)
    unsigned short* attg = (unsigned short*)((char*)out + (size_t)b * 46080 + 22528);

    // ================= phase 1: staging =================
    if (t < 192) {                       // xb pad cols 180..191
        const int n = t / 3, c = t % 3;
        *reinterpret_cast<uint2*>(xb + n * XB_P + 180 + 4 * c) = make_uint2(0u, 0u);
    } else if (t < 256) {                // attg pad cols 180..183
        const int n = t - 192;
        ushort4b z = {0, 0, 0, 0};
        *reinterpret_cast<ushort4b*>(attg + n * ATT_P + 180) = z;
    }
    {
        const float* xw = x + (size_t)b * 11520;
        for (int i = t; i < 64 * 45; i += NT) {
            const int n = i / 45, c4 = i % 45;
            const float4 v = *reinterpret_cast<const float4*>(xw + i * 4);
            *reinterpret_cast<uint2*>(xb + n * XB_P + c4 * 4) =
                make_uint2(bf2pk(v.x, v.y), bf2pk(v.z, v.w));
        }
    }
    if (t < 256) {                       // bpe -> LDS f32
        const float4 v = *reinterpret_cast<const float4*>(bpe + (size_t)b * 1024 + t * 4);
        *reinterpret_cast<float4*>(bpes + (t >> 2) * 20 + (t & 3) * 4) = v;
    }
    __syncthreads();

    // ================= phase 2a: dB (f16, full 64x64) =================
    {
        const int ti = t >> 4, tj = t & 15;   // rows {ti, ti+32}, cols {tj+16e}
        float acc0[4] = {0.f, 0.f, 0.f, 0.f};
        float acc1[4] = {0.f, 0.f, 0.f, 0.f};
        #pragma unroll
        for (int k4 = 0; k4 < 4; ++k4) {
            const float4 a0 = *reinterpret_cast<const float4*>(bpes + ti * 20 + 4 * k4);
            const float4 a1 = *reinterpret_cast<const float4*>(bpes + (ti + 32) * 20 + 4 * k4);
            #pragma unroll
            for (int e = 0; e < 4; ++e) {
                const float4 bb = *reinterpret_cast<const float4*>(bpes + (tj + 16 * e) * 20 + 4 * k4);
                float d;
                d = a0.x - bb.x; acc0[e] += d * d;
                d = a0.y - bb.y; acc0[e] += d * d;
                d = a0.z - bb.z; acc0[e] += d * d;
                d = a0.w - bb.w; acc0[e] += d * d;
                d = a1.x - bb.x; acc1[e] += d * d;
                d = a1.y - bb.y; acc1[e] += d * d;
                d = a1.z - bb.z; acc1[e] += d * d;
                d = a1.w - bb.w; acc1[e] += d * d;
            }
        }
        #pragma unroll
        for (int e = 0; e < 4; ++e) {
            dBs[ti * DB_P + tj + 16 * e] =
                __half_as_ushort(__float2half_rn(sqrtf(acc0[e])));
            dBs[(ti + 32) * DB_P + tj + 16 * e] =
                __half_as_ushort(__float2half_rn(sqrtf(acc1[e])));
        }
    }
    // NOTE: no barrier here — dB is first read in attn, after the QKV barrier.

    // ================= passes: QKV (3 heads) + attention =================
    for (int pass = 0; pass < 2; ++pass) {
        if (pass) __syncthreads();       // attn(pass-1) done reading qk/vT

        // ---- QKV: 18 tiles (9 segs x 2 halves), kk-outer, 2-3 tiles/wave ----
        {
            f32x4 acc[3][4];
            const unsigned short* wrow[3];
            bool has[3], arow_ok[3];
            int whichv[3], hhl[3], halfv[3];
            #pragma unroll
            for (int ti = 0; ti < 3; ++ti) {
                const int tl = w + 8 * ti;
                has[ti] = (tl < 18);
                const int tls = has[ti] ? tl : 0;
                const int segl = tls >> 1;            // 0..8
                halfv[ti] = tls & 1;
                whichv[ti] = segl / 3;
                hhl[ti] = segl % 3;
                const int hg = 3 * pass + hhl[ti];
                const int wseg = whichv[ti] * 6 + hg; // wqr seg
                const int ddr = halfv[ti] * 16 + lr;
                arow_ok[ti] = (ddr < 30);
                wrow[ti] = wqr + (size_t)(wseg * 30 + (arow_ok[ti] ? ddr : 0)) * WK;
                const int ddb = halfv[ti] * 16 + g * 4;
                const int cbase = whichv[ti] * 180 + hg * 30;
                f32x4 binit;
                #pragma unroll
                for (int i = 0; i < 4; ++i)
                    binit[i] = (ddb + i < 30) ? qkv_b[cbase + ddb + i] : 0.f;
                #pragma unroll
                for (int mt = 0; mt < 4; ++mt) acc[ti][mt] = binit;
            }
            #pragma unroll
            for (int kk = 0; kk < 6; ++kk) {
                short8b xf[4];
                #pragma unroll
                for (int mt = 0; mt < 4; ++mt)
                    xf[mt] = *reinterpret_cast<const short8b*>(
                        xb + (mt * 16 + lr) * XB_P + kk * 32 + g * 8);
                #pragma unroll
                for (int ti = 0; ti < 3; ++ti) {
                    if (!has[ti]) continue;
                    short8b wfv;
                    if (arow_ok[ti])
                        wfv = *reinterpret_cast<const short8b*>(wrow[ti] + kk * 32 + g * 8);
                    else
                        wfv = short8b{0, 0, 0, 0, 0, 0, 0, 0};
                    #pragma unroll
                    for (int mt = 0; mt < 4; ++mt)
                        acc[ti][mt] = __builtin_amdgcn_mfma_f32_16x16x32_bf16(
                            wfv, xf[mt], acc[ti][mt], 0, 0, 0);
                }
            }
            // epilogue: lane holds chans ddb..ddb+3 for tok = mt*16+lr.
            // pad rows/cols receive computed zeros (q/k cols 30,31; vT rows 30,31).
            #pragma unroll
            for (int ti = 0; ti < 3; ++ti) {
                if (!has[ti]) continue;
                const int ddb = halfv[ti] * 16 + g * 4;
                #pragma unroll
                for (int mt = 0; mt < 4; ++mt) {
                    const int tok = mt * 16 + lr;
                    float v0 = acc[ti][mt][0], v1 = acc[ti][mt][1];
                    float v2 = acc[ti][mt][2], v3 = acc[ti][mt][3];
                    if (whichv[ti] == 0) { v0 *= SCALE; v1 *= SCALE; v2 *= SCALE; v3 *= SCALE; }
                    if (whichv[ti] < 2) {
                        *reinterpret_cast<uint2*>(
                            qk + tok * QK_P + hhl[ti] * 64 + whichv[ti] * 32 + ddb) =
                            make_uint2(bf2pk(v0, v1), bf2pk(v2, v3));
                    } else {
                        const int c = (tok & 32) + ((tok >> 2) & 3) * 8 + ((tok >> 4) & 1) * 4 + (tok & 3);
                        unsigned short* vb = vT + hhl[ti] * 2304 + ddb * VT_P + c;
                        vb[0 * VT_P] = bf1(v0);
                        vb[1 * VT_P] = bf1(v1);
                        vb[2 * VT_P] = bf1(v2);
                        vb[3 * VT_P] = bf1(v3);
                    }
                }
            }
        }
        __syncthreads();

        // ---- attention: 12 units (hh, mt) over 8 waves ----
        for (int u = w; u < 12; u += 8) {
            const int hh = u >> 2, mt = u & 3;
            const int h = 3 * pass + hh;
            const int tok = mt * 16 + lr;
            const unsigned short* qkh = qk + hh * 64;
            // prefetch all fragments
            const short8b qf = *reinterpret_cast<const short8b*>(
                qkh + tok * QK_P + g * 8);
            short8b kf[4];
            #pragma unroll
            for (int jt = 0; jt < 4; ++jt)
                kf[jt] = *reinterpret_cast<const short8b*>(
                    qkh + (jt * 16 + lr) * QK_P + 32 + g * 8);
            short8b vf[2][2];
            #pragma unroll
            for (int ntd = 0; ntd < 2; ++ntd)
                #pragma unroll
                for (int ks = 0; ks < 2; ++ks)
                    vf[ntd][ks] = *reinterpret_cast<const short8b*>(
                        vT + hh * 2304 + (ntd * 16 + lr) * VT_P + ks * 32 + g * 8);
            const float itau = 1.f / fmaxf(tau[h], 1e-6f);
            // S^T = mfma(K, Q), C-init = -dB/tau ; lane: tok=mt*16+lr, j=jt*16+g*4+i
            f32x4 s[4];
            #pragma unroll
            for (int jt = 0; jt < 4; ++jt) {
                const ushort4b du = *reinterpret_cast<const ushort4b*>(
                    dBs + tok * DB_P + jt * 16 + g * 4);
                #pragma unroll
                for (int i = 0; i < 4; ++i)
                    s[jt][i] = -itau * __half2float(__ushort_as_half(du[i]));
            }
            #pragma unroll
            for (int jt = 0; jt < 4; ++jt)
                s[jt] = __builtin_amdgcn_mfma_f32_16x16x32_bf16(kf[jt], qf, s[jt], 0, 0, 0);
            // softmax over j: balanced trees + 2 shfl steps
            float m4[4], a4[4];
            #pragma unroll
            for (int i = 0; i < 4; ++i)
                m4[i] = fmaxf(fmaxf(s[0][i], s[1][i]), fmaxf(s[2][i], s[3][i]));
            float mx = fmaxf(fmaxf(m4[0], m4[1]), fmaxf(m4[2], m4[3]));
            mx = fmaxf(mx, __shfl_xor(mx, 16));
            mx = fmaxf(mx, __shfl_xor(mx, 32));
            #pragma unroll
            for (int jt = 0; jt < 4; ++jt)
                #pragma unroll
                for (int i = 0; i < 4; ++i)
                    s[jt][i] = __expf(s[jt][i] - mx);
            #pragma unroll
            for (int i = 0; i < 4; ++i)
                a4[i] = (s[0][i] + s[1][i]) + (s[2][i] + s[3][i]);
            float sum = (a4[0] + a4[1]) + (a4[2] + a4[3]);
            sum += __shfl_xor(sum, 16);
            sum += __shfl_xor(sum, 32);
            const float inv = 1.f / sum;
            // pack P into PV B-fragments (slot bijection matches vT column permutation)
            union { short8b v; unsigned int u[4]; } pb[2];
            #pragma unroll
            for (int ks = 0; ks < 2; ++ks) {
                pb[ks].u[0] = bf2pk(s[2 * ks][0] * inv, s[2 * ks][1] * inv);
                pb[ks].u[1] = bf2pk(s[2 * ks][2] * inv, s[2 * ks][3] * inv);
                pb[ks].u[2] = bf2pk(s[2 * ks + 1][0] * inv, s[2 * ks + 1][1] * inv);
                pb[ks].u[3] = bf2pk(s[2 * ks + 1][2] * inv, s[2 * ks + 1][3] * inv);
            }
            // PV: D[dd][tok]; att col = h*30+dd
            f32x4 o0 = {0.f, 0.f, 0.f, 0.f}, o1 = {0.f, 0.f, 0.f, 0.f};
            o0 = __builtin_amdgcn_mfma_f32_16x16x32_bf16(vf[0][0], pb[0].v, o0, 0, 0, 0);
            o1 = __builtin_amdgcn_mfma_f32_16x16x32_bf16(vf[1][0], pb[0].v, o1, 0, 0, 0);
            o0 = __builtin_amdgcn_mfma_f32_16x16x32_bf16(vf[0][1], pb[1].v, o0, 0, 0, 0);
            o1 = __builtin_amdgcn_mfma_f32_16x16x32_bf16(vf[1][1], pb[1].v, o1, 0, 0, 0);
            {
                const int col0 = h * 30 + g * 4;
                *reinterpret_cast<uint2*>(attg + tok * ATT_P + col0) =
                    make_uint2(bf2pk(o0[0], o0[1]), bf2pk(o0[2], o0[3]));
                const int col1 = h * 30 + 16 + g * 4;
                if (g < 3) {
                    *reinterpret_cast<uint2*>(attg + tok * ATT_P + col1) =
                        make_uint2(bf2pk(o1[0], o1[1]), bf2pk(o1[2], o1[3]));
                } else {   // dd 28,29 only
                    *reinterpret_cast<unsigned int*>(attg + tok * ATT_P + col1) =
                        bf2pk(o1[0], o1[1]);
                }
            }
        }
    }
    __syncthreads();   // all attg writes drained & visible

    // ================= proj: D[out-chan][tok], 6 tiles/wave sharing attf =================
    {
        const int mt = w & 3;                 // wave's token group
        const int ntb = (w >> 2) * 6;         // nt = ntb..ntb+5
        short8b attf[6];
        #pragma unroll
        for (int kk = 0; kk < 6; ++kk) {
            if (kk == 5 && g == 3)            // att cols 184..191 don't exist
                attf[kk] = short8b{0, 0, 0, 0, 0, 0, 0, 0};
            else
                attf[kk] = *reinterpret_cast<const short8b*>(
                    attg + (mt * 16 + lr) * ATT_P + kk * 32 + g * 8);
        }
        f32x4 pacc[6];
        #pragma unroll
        for (int q6 = 0; q6 < 6; ++q6) {
            const int nt = ntb + q6;
            const unsigned short* wrow = wpr + (size_t)(nt * 16 + lr) * WK;
            const int cb = nt * 16 + g * 4;
            f32x4 acc;
            #pragma unroll
            for (int i = 0; i < 4; ++i)
                acc[i] = (cb + i < 180) ? proj_b[cb + i] : 0.f;
            #pragma unroll
            for (int kk = 0; kk < 6; ++kk) {
                const short8b wf = *reinterpret_cast<const short8b*>(wrow + kk * 32 + g * 8);
                acc = __builtin_amdgcn_mfma_f32_16x16x32_bf16(wf, attf[kk], acc, 0, 0, 0);
            }
            pacc[q6] = acc;
        }
        __syncthreads();   // all attg reads complete before out stores overwrite
        #pragma unroll
        for (int q6 = 0; q6 < 6; ++q6) {
            const int nt = ntb + q6;
            const int cb = nt * 16 + g * 4;
            if (cb < 177) {
                const int tok = mt * 16 + lr;
                *reinterpret_cast<float4*>(out + ((size_t)b * 64 + tok) * 180 + cb) =
                    make_float4(pacc[q6][0], pacc[q6][1], pacc[q6][2], pacc[q6][3]);
            }
        }
    }
}

extern "C" void kernel_launch(void* const* d_in, const int* in_sizes, int n_in,
                              void* d_out, int out_size, void* d_ws, size_t ws_size,
                              hipStream_t stream) {
    (void)in_sizes; (void)n_in; (void)out_size; (void)ws_size;
    const float* x      = (const float*)d_in[0];
    const float* bpe    = (const float*)d_in[1];
    const float* qkv_w  = (const float*)d_in[2];
    const float* qkv_b  = (const float*)d_in[3];
    const float* proj_w = (const float*)d_in[4];
    const float* proj_b = (const float*)d_in[5];
    const float* tau    = (const float*)d_in[6];

    unsigned short* wqr = (unsigned short*)d_ws;     // 540*192 bf16 = 207360 B
    unsigned short* wpr = wqr + 540 * WK;            // 192*192 bf16 =  73728 B

    prep_weights<<<(540 * WK + WK * WK + 255) / 256, 256, 0, stream>>>(
        qkv_w, proj_w, wqr, wpr);

    (void)hipFuncSetAttribute((const void*)waga_mfma,
                              hipFuncAttributeMaxDynamicSharedMemorySize,
                              LDS_BYTES);
    waga_mfma<<<NWIN, NT, LDS_BYTES, stream>>>(x, bpe, wqr, wpr, qkv_b, proj_b, tau,
                                               (float*)d_out);
}